// Round 6
// baseline (1611.771 us; speedup 1.0000x reference)
//
#include <hip/hip_runtime.h>
#include <stdint.h>

#define Bdim 4
#define Sdim 2048
#define Ddim 512
#define Hdim 8
#define Mdim (Bdim*Sdim)   // 8192
#define Shalf 1024

typedef __attribute__((ext_vector_type(8))) short bf16x8;
typedef __attribute__((ext_vector_type(4))) float f32x4;
typedef __attribute__((ext_vector_type(4))) int i32x4;

#define SCALE 0.044194173824159216f   // 1/sqrt(512)
#define LOG2E 1.4426950408889634f

__device__ __forceinline__ unsigned short f2bf(float f){
  union { float f; unsigned int u; } v; v.f = f;
  unsigned int u = v.u + 0x7FFFu + ((v.u >> 16) & 1u);   // RNE
  return (unsigned short)(u >> 16);
}

__device__ __forceinline__ void gl_lds16(const void* g, void* l){
  __builtin_amdgcn_global_load_lds(
      (const __attribute__((address_space(1))) unsigned int*)g,
      (__attribute__((address_space(3))) unsigned int*)l, 16, 0, 0);
}

// parity permutation: row m (b*2048+s) -> b*2048 + (s&1)*1024 + (s>>1)
__device__ __forceinline__ int permrow(int m){
  return (m & ~2047) | ((m & 1) << 10) | ((m & 2047) >> 1);
}

// ---------------- prep: x fp32 -> bf16 ----------------
__global__ void cvt_x(const float* __restrict__ x, unsigned short* __restrict__ xb, int n8){
  int i = blockIdx.x*blockDim.x + threadIdx.x;
  if (i >= n8) return;
  const float4* p = (const float4*)x + (size_t)i*2;
  float4 a = p[0], b = p[1];
  union { unsigned short s[8]; i32x4 v; } o;
  o.s[0]=f2bf(a.x); o.s[1]=f2bf(a.y); o.s[2]=f2bf(a.z); o.s[3]=f2bf(a.w);
  o.s[4]=f2bf(b.x); o.s[5]=f2bf(b.y); o.s[6]=f2bf(b.z); o.s[7]=f2bf(b.w);
  ((i32x4*)xb)[i] = o.v;
}

// ---------------- prep: W fp32 [k][n] -> bf16 Wt [type*H+h][n][k] ----------------
__global__ void twk(const float* __restrict__ Wq, const float* __restrict__ Wk,
                    const float* __restrict__ Wv, unsigned short* __restrict__ Wt){
  __shared__ float t[32][33];
  int z = blockIdx.z;                       // type*H + h
  const float* W = (z < Hdim ? Wq : (z < 2*Hdim ? Wk : Wv)) + (size_t)(z % Hdim)*Ddim*Ddim;
  int n0 = blockIdx.x*32, k0 = blockIdx.y*32;
  #pragma unroll
  for (int i=0;i<4;i++){
    int k = k0 + threadIdx.y + i*8;
    t[threadIdx.y + i*8][threadIdx.x] = W[(size_t)k*Ddim + n0 + threadIdx.x];
  }
  __syncthreads();
  #pragma unroll
  for (int i=0;i<4;i++){
    int n = threadIdx.y + i*8;
    Wt[(size_t)z*Ddim*Ddim + (size_t)(n0+n)*Ddim + k0 + threadIdx.x] = f2bf(t[threadIdx.x][n]);
  }
}

// ---------------- projection: Q/K parity-permuted rows, V -> Vt [d][m'] ----------------
__launch_bounds__(256, 2)
__global__ void proj(const unsigned short* __restrict__ xb,
                     const unsigned short* __restrict__ Wt,
                     unsigned short* __restrict__ Qb,
                     unsigned short* __restrict__ Kb,
                     unsigned short* __restrict__ Vtb,
                     int h0, int g)
{
  __shared__ unsigned short smem[16640];    // A[0..4096) B[4096..8192) ; epilogue: [128][130]
  int tid = threadIdx.x, w = tid>>6, lane = tid&63;
  int wm = w>>1, wn = w&1;
  int y = blockIdx.y, g4 = 4*g;
  int type = y / g4; int rem = y - type*g4;
  int hrel = rem >> 2, nt = rem & 3;
  int m0 = blockIdx.x * 128, n0 = nt * 128;
  int l15 = lane&15, l4 = lane>>4;

  const unsigned short* Bsrc = Wt + (size_t)(type*Hdim + h0 + hrel)*Ddim*Ddim;

  f32x4 acc[4][4];
  #pragma unroll
  for (int i=0;i<4;i++)
    #pragma unroll
    for (int j=0;j<4;j++){ f32x4 z={0.f,0.f,0.f,0.f}; acc[i][j]=z; }

  for (int kt=0; kt<16; ++kt){
    int k0 = kt*32;
    #pragma unroll
    for (int i=0;i<2;i++){
      int row = i*64 + w*16 + (lane>>2);
      int cb  = lane&3;
      gl_lds16(xb   + (size_t)(m0+row)*Ddim + k0 + cb*8, (char*)smem + i*4096 + w*1024);
      gl_lds16(Bsrc + (size_t)(n0+row)*Ddim + k0 + cb*8, (char*)smem + 8192 + i*4096 + w*1024);
    }
    __syncthreads();
    bf16x8 af[4], bfr[4];
    #pragma unroll
    for (int i=0;i<4;i++){
      af[i]  = *(const bf16x8*)&smem[(wm*64 + i*16 + l15)*32 + l4*8];
      bfr[i] = *(const bf16x8*)&smem[4096 + (wn*64 + i*16 + l15)*32 + l4*8];
    }
    #pragma unroll
    for (int i=0;i<4;i++)
      #pragma unroll
      for (int j=0;j<4;j++)
        acc[i][j] = __builtin_amdgcn_mfma_f32_16x16x32_bf16(af[i], bfr[j], acc[i][j], 0,0,0);
    __syncthreads();
  }

  if (type < 2){
    unsigned short* Ob = (type==0 ? Qb : Kb) + (size_t)hrel*Mdim*Ddim;
    #pragma unroll
    for (int i=0;i<4;i++){
      int mb = m0 + wm*64 + i*16 + (l4<<2);
      #pragma unroll
      for (int j=0;j<4;j++){
        int col = n0 + wn*64 + j*16 + l15;
        #pragma unroll
        for (int r=0;r<4;r++)
          Ob[(size_t)permrow(mb + r)*Ddim + col] = f2bf(acc[i][j][r]);
      }
    }
  } else {
    // bounce-transpose tile through LDS, write Vt[d][m'] with parity-split columns
    #pragma unroll
    for (int i=0;i<4;i++){
      int ml = wm*64 + i*16 + (l4<<2);
      #pragma unroll
      for (int j=0;j<4;j++){
        int nl = wn*64 + j*16 + l15;
        #pragma unroll
        for (int r=0;r<4;r++)
          smem[(ml + r)*130 + nl] = f2bf(acc[i][j][r]);
      }
    }
    __syncthreads();
    unsigned short* Ovt = Vtb + (size_t)hrel*Ddim*Mdim;
    int bb  = m0 >> 11;
    int ib0 = (m0 & 2047) >> 1;     // i-base within parity block (64 i per tile)
    #pragma unroll
    for (int c=0;c<8;c++){
      int nl = c*16 + (tid>>4);     // d-local 0..127
      int il = (tid&15)*4;          // i-local 0..60 step 4
      #pragma unroll
      for (int pp=0; pp<2; pp++){
        union { unsigned short s[4]; uint2 v; } pk;
        #pragma unroll
        for (int ii=0;ii<4;ii++) pk.s[ii] = smem[(2*(il+ii)+pp)*130 + nl];
        *(uint2*)&Ovt[(size_t)(n0+nl)*Mdim + bb*Sdim + pp*Shalf + ib0 + il] = pk.v;
      }
    }
  }
}

// ---------------- staging: lane-linear LDS blocks, RELATIVE indices + internal clamp ----
// 4 waves stage 32 K-blocks + 32 V-blocks of 1 KB each (8+8 loads per wave).
// Clamped rows/cols are guaranteed fully-masked because tiles are 32-aligned.
__device__ __forceinline__ void stage_tile(const unsigned short* Kbase, int krow0,
                                           const unsigned short* Vblk, int vcol0,
                                           char* KsB, char* VsB, int w, int lane)
{
  int l15 = lane&15, l4 = lane>>4;
  #pragma unroll
  for (int jj=0;jj<8;jj++){
    int bi = w*8 + jj;
    // K block bi: rows (bi>>4)*16 + l15, 16B-chunk g = (bi&15)*4 + l4
    {
      int r = ((bi>>4)<<4) + l15;
      int g = ((bi&15)<<2) + l4;
      int row = krow0 + r;
      row = row < 0 ? 0 : (row > Shalf-1 ? Shalf-1 : row);
      gl_lds16(Kbase + (size_t)row*Ddim + g*8, KsB + bi*1024);
    }
    // V block bi: d-rows bi*16 + l15, key-chunk l4 (8 keys)
    {
      int d = (bi<<4) + l15;
      int col = vcol0 + l4*8;
      col = col < 0 ? 0 : (col > Shalf-8 ? Shalf-8 : col);
      gl_lds16(Vblk + (size_t)d*Mdim + col, VsB + bi*1024);
    }
  }
}

// ---------------- flash attention over parity-dense sequences ----------------
#define NDENSE 32
#define NSPEC 3
#define NT (NDENSE + NSPEC)

__launch_bounds__(256, 2)
__global__ void attn(const unsigned short* __restrict__ Qb,
                     const unsigned short* __restrict__ Kb,
                     const unsigned short* __restrict__ Vtb,
                     float* __restrict__ out)
{
  __shared__ char lds[32768 + 32768 + 4096];   // Ks | Vs | Ps (single-buffered)
  int tid = threadIdx.x, w = tid>>6, lane = tid&63;
  int l15 = lane&15, l4 = lane>>4;
  // grid = (z, qc): linear id = z + 64*qc -> XCD = z%8, so all q-chunks of one
  // (h,b,p) stream land on the same XCD's L2.
  int z  = blockIdx.x;              // ((h*4+b)*2+p)
  int qc = blockIdx.y;              // 0..15 (64 queries each)
  int p  = z & 1; int zb = z >> 1; int b = zb & 3; int h = zb >> 2;

  const unsigned short* Qp     = Qb + (size_t)h*Mdim*Ddim + (size_t)(b*Sdim + p*Shalf)*Ddim;
  const unsigned short* Ksame  = Kb + (size_t)h*Mdim*Ddim + (size_t)(b*Sdim + p*Shalf)*Ddim;
  const unsigned short* Kopp   = Kb + (size_t)h*Mdim*Ddim + (size_t)(b*Sdim + (1-p)*Shalf)*Ddim;
  const unsigned short* Vt     = Vtb + (size_t)h*Ddim*Mdim;
  int csame = b*Sdim + p*Shalf;
  int copp  = b*Sdim + (1-p)*Shalf;
  int i0 = qc*64;
  int j0 = i0 - 32 + 32*p;          // parity-trimmed 32-aligned neighbor-window base

  // Q fragments in registers: rows i0 + w*16 + l15
  bf16x8 qa[16];
  {
    const unsigned short* qr = Qp + (size_t)(i0 + w*16 + l15)*Ddim;
    #pragma unroll
    for (int ks=0;ks<16;ks++) qa[ks] = *(const bf16x8*)&qr[ks*32 + l4*8];
  }

  f32x4 acc[32];
  #pragma unroll
  for (int n=0;n<32;n++){ f32x4 zz={0.f,0.f,0.f,0.f}; acc[n]=zz; }
  float ms[4], ls[4];
  #pragma unroll
  for (int r=0;r<4;r++){ ms[r] = -3.0e38f; ls[r] = 0.f; }

  char* KsB = lds;
  char* VsB = lds + 32768;

  // prologue: stage tile 0 (dense, fully in-range)
  stage_tile(Ksame, 0, Vt + csame, 0, KsB, VsB, w, lane);

  for (int t=0; t<NT; ++t){
    asm volatile("s_waitcnt vmcnt(0)" ::: "memory");   // own staging loads done
    __builtin_amdgcn_s_barrier();                      // tile t visible to all waves
    __builtin_amdgcn_sched_barrier(0);

    // QK^T : S[16 q][32 keys] per wave
    f32x4 sc[2];
    #pragma unroll
    for (int sub=0; sub<2; ++sub){
      f32x4 zz = {0.f,0.f,0.f,0.f}; sc[sub] = zz;
      #pragma unroll
      for (int ks=0;ks<16;ks++){
        bf16x8 kb = *(const bf16x8*)(KsB + (sub*16+ks)*1024 + (l4*16+l15)*16);
        sc[sub] = __builtin_amdgcn_mfma_f32_16x16x32_bf16(qa[ks], kb, sc[sub], 0,0,0);
      }
    }

    // softmax with defer-max; cross-lane max only when some lane exceeds ms+8
    float s0v[4], s1v[4], lmax[4];
    bool spec = (t >= NDENSE);
    int tbase = spec ? (j0 + (t-NDENSE)*32) : 0;
    #pragma unroll
    for (int r=0;r<4;r++){
      float s0 = sc[0][r]*SCALE, s1 = sc[1][r]*SCALE;
      if (spec){
        int iq = i0 + w*16 + l4*4 + r;
        int jA = tbase + l15;
        int jB = jA + 16;
        int tgt = iq - 1 + 2*p;
        bool vA = (jA>=0) & (jA<Shalf) & ((jA==iq) | (jA==tgt));
        bool vB = (jB>=0) & (jB<Shalf) & ((jB==iq) | (jB==tgt));
        if(!vA) s0 = -1e30f;
        if(!vB) s1 = -1e30f;
      }
      s0v[r]=s0; s1v[r]=s1;
      lmax[r] = fmaxf(s0, s1);
    }
    bool need = (lmax[0] > ms[0]+8.f) | (lmax[1] > ms[1]+8.f) |
                (lmax[2] > ms[2]+8.f) | (lmax[3] > ms[3]+8.f);
    if (__any(need)){
      #pragma unroll
      for (int r=0;r<4;r++){
        float tm = lmax[r];
        tm = fmaxf(tm, __shfl_xor(tm, 1));
        tm = fmaxf(tm, __shfl_xor(tm, 2));
        tm = fmaxf(tm, __shfl_xor(tm, 4));
        tm = fmaxf(tm, __shfl_xor(tm, 8));
        float nm = fmaxf(ms[r], tm);
        float rs = exp2f((ms[r]-nm)*LOG2E);
        ms[r] = nm; ls[r] *= rs;
        #pragma unroll
        for (int n=0;n<32;n++) acc[n][r] *= rs;
      }
    }

    // P = exp(s - m), row-sum, store to per-wave LDS in A-frag layout
    char* PsB = lds + 65536 + w*1024;
    #pragma unroll
    for (int r=0;r<4;r++){
      float p0 = exp2f((s0v[r]-ms[r])*LOG2E);
      float p1 = exp2f((s1v[r]-ms[r])*LOG2E);
      float rs = p0 + p1;
      rs += __shfl_xor(rs, 1);
      rs += __shfl_xor(rs, 2);
      rs += __shfl_xor(rs, 4);
      rs += __shfl_xor(rs, 8);
      ls[r] += rs;
      int q = l4*4 + r;
      *(unsigned short*)(PsB + (((l15>>3)*16 + q)*16 + (l15&7)*2))     = f2bf(p0);
      *(unsigned short*)(PsB + (((2+(l15>>3))*16 + q)*16 + (l15&7)*2)) = f2bf(p1);
    }
    asm volatile("s_waitcnt lgkmcnt(0)" ::: "memory");
    __builtin_amdgcn_sched_barrier(0);
    bf16x8 pa = *(const bf16x8*)(PsB + (l4*16+l15)*16);

    // PV: acc[n] over 32 d-fragments
    #pragma unroll
    for (int n=0;n<32;n++){
      bf16x8 vb = *(const bf16x8*)(VsB + n*1024 + (l4*16+l15)*16);
      acc[n] = __builtin_amdgcn_mfma_f32_16x16x32_bf16(pa, vb, acc[n], 0,0,0);
    }

    __builtin_amdgcn_sched_barrier(0);
    __builtin_amdgcn_s_barrier();                      // all waves done reading tile t
    __builtin_amdgcn_sched_barrier(0);
    if (t + 1 < NT){
      if (t + 1 < NDENSE)
        stage_tile(Ksame, (t+1)*32, Vt + csame, (t+1)*32, KsB, VsB, w, lane);
      else {
        int tt = t + 1 - NDENSE;
        stage_tile(Kopp, j0 + tt*32, Vt + copp, j0 + tt*32, KsB, VsB, w, lane);
      }
    }
  }

  // epilogue: normalize + head-mean via atomics; out row = b*2048 + 2i + p
  #pragma unroll
  for (int r=0;r<4;r++){
    float inv = 0.125f / ls[r];
    int i = i0 + w*16 + l4*4 + r;
    float* orow = out + (size_t)(b*Sdim + 2*i + p)*Ddim;
    #pragma unroll
    for (int n=0;n<32;n++)
      atomicAdd(&orow[n*16 + l15], acc[n][r]*inv);
  }
}

extern "C" void kernel_launch(void* const* d_in, const int* in_sizes, int n_in,
                              void* d_out, int out_size, void* d_ws, size_t ws_size,
                              hipStream_t stream)
{
  (void)in_sizes; (void)n_in;
  const float* x  = (const float*)d_in[0];
  const float* Wq = (const float*)d_in[1];
  const float* Wk = (const float*)d_in[2];
  const float* Wv = (const float*)d_in[3];
  float* out = (float*)d_out;

  const size_t xb_bytes = (size_t)Mdim*Ddim*2;        // 8 MB
  const size_t wt_bytes = (size_t)3*Hdim*Ddim*Ddim*2; // 12.6 MB
  const size_t per_head = (size_t)Mdim*Ddim*2;        // 8.4 MB

  int g = 8;
  while (g > 1 && xb_bytes + wt_bytes + 3*(size_t)g*per_head > ws_size) g >>= 1;

  unsigned short* xb  = (unsigned short*)d_ws;
  unsigned short* Wt  = (unsigned short*)((char*)d_ws + xb_bytes);
  unsigned short* Qb  = (unsigned short*)((char*)d_ws + xb_bytes + wt_bytes);
  unsigned short* Kb  = Qb + (size_t)g*Mdim*Ddim;
  unsigned short* Vtb = Kb + (size_t)g*Mdim*Ddim;

  hipMemsetAsync(d_out, 0, (size_t)out_size*sizeof(float), stream);
  cvt_x<<<dim3(Mdim*Ddim/8/256), dim3(256), 0, stream>>>(x, xb, Mdim*Ddim/8);
  twk<<<dim3(Ddim/32, Ddim/32, 3*Hdim), dim3(32,8), 0, stream>>>(Wq, Wk, Wv, Wt);

  for (int h0 = 0; h0 < Hdim; h0 += g){
    proj<<<dim3(Mdim/128, 12*g), dim3(256), 0, stream>>>(xb, Wt, Qb, Kb, Vtb, h0, g);
    attn<<<dim3(g*Bdim*2, Shalf/64 /*qc=16*/), dim3(256), 0, stream>>>(Qb, Kb, Vtb, out);
  }
}

// Round 7
// 586.790 us; speedup vs baseline: 2.7468x; 2.7468x over previous
//
#include <hip/hip_runtime.h>
#include <stdint.h>

#define Bdim 4
#define Sdim 2048
#define Ddim 512
#define Hdim 8
#define Mdim (Bdim*Sdim)   // 8192
#define Shalf 1024

typedef __attribute__((ext_vector_type(8))) short bf16x8;
typedef __attribute__((ext_vector_type(4))) float f32x4;
typedef __attribute__((ext_vector_type(4))) int i32x4;

#define SCALE 0.044194173824159216f   // 1/sqrt(512)
#define LOG2E 1.4426950408889634f

__device__ __forceinline__ unsigned short f2bf(float f){
  union { float f; unsigned int u; } v; v.f = f;
  unsigned int u = v.u + 0x7FFFu + ((v.u >> 16) & 1u);   // RNE
  return (unsigned short)(u >> 16);
}

__device__ __forceinline__ void gl_lds16(const void* g, void* l){
  __builtin_amdgcn_global_load_lds(
      (const __attribute__((address_space(1))) unsigned int*)g,
      (__attribute__((address_space(3))) unsigned int*)l, 16, 0, 0);
}

// parity permutation: row m (b*2048+s) -> b*2048 + (s&1)*1024 + (s>>1)
__device__ __forceinline__ int permrow(int m){
  return (m & ~2047) | ((m & 1) << 10) | ((m & 2047) >> 1);
}

// ---------------- prep: x fp32 -> bf16 ----------------
__global__ void cvt_x(const float* __restrict__ x, unsigned short* __restrict__ xb, int n8){
  int i = blockIdx.x*blockDim.x + threadIdx.x;
  if (i >= n8) return;
  const float4* p = (const float4*)x + (size_t)i*2;
  float4 a = p[0], b = p[1];
  union { unsigned short s[8]; i32x4 v; } o;
  o.s[0]=f2bf(a.x); o.s[1]=f2bf(a.y); o.s[2]=f2bf(a.z); o.s[3]=f2bf(a.w);
  o.s[4]=f2bf(b.x); o.s[5]=f2bf(b.y); o.s[6]=f2bf(b.z); o.s[7]=f2bf(b.w);
  ((i32x4*)xb)[i] = o.v;
}

// ---------------- prep: W fp32 [k][n] -> bf16 Wt [type*H+h][n][k] ----------------
__global__ void twk(const float* __restrict__ Wq, const float* __restrict__ Wk,
                    const float* __restrict__ Wv, unsigned short* __restrict__ Wt){
  __shared__ float t[32][33];
  int z = blockIdx.z;                       // type*H + h
  const float* W = (z < Hdim ? Wq : (z < 2*Hdim ? Wk : Wv)) + (size_t)(z % Hdim)*Ddim*Ddim;
  int n0 = blockIdx.x*32, k0 = blockIdx.y*32;
  #pragma unroll
  for (int i=0;i<4;i++){
    int k = k0 + threadIdx.y + i*8;
    t[threadIdx.y + i*8][threadIdx.x] = W[(size_t)k*Ddim + n0 + threadIdx.x];
  }
  __syncthreads();
  #pragma unroll
  for (int i=0;i<4;i++){
    int n = threadIdx.y + i*8;
    Wt[(size_t)z*Ddim*Ddim + (size_t)(n0+n)*Ddim + k0 + threadIdx.x] = f2bf(t[threadIdx.x][n]);
  }
}

// ---------------- projection: Q/K parity-permuted rows, V -> Vt [d][m'] ----------------
__launch_bounds__(256, 2)
__global__ void proj(const unsigned short* __restrict__ xb,
                     const unsigned short* __restrict__ Wt,
                     unsigned short* __restrict__ Qb,
                     unsigned short* __restrict__ Kb,
                     unsigned short* __restrict__ Vtb,
                     int h0, int g)
{
  __shared__ unsigned short smem[16640];    // A[0..4096) B[4096..8192) ; epilogue: [128][130]
  int tid = threadIdx.x, w = tid>>6, lane = tid&63;
  int wm = w>>1, wn = w&1;
  int y = blockIdx.y, g4 = 4*g;
  int type = y / g4; int rem = y - type*g4;
  int hrel = rem >> 2, nt = rem & 3;
  int m0 = blockIdx.x * 128, n0 = nt * 128;
  int l15 = lane&15, l4 = lane>>4;

  const unsigned short* Bsrc = Wt + (size_t)(type*Hdim + h0 + hrel)*Ddim*Ddim;

  f32x4 acc[4][4];
  #pragma unroll
  for (int i=0;i<4;i++)
    #pragma unroll
    for (int j=0;j<4;j++){ f32x4 z={0.f,0.f,0.f,0.f}; acc[i][j]=z; }

  for (int kt=0; kt<16; ++kt){
    int k0 = kt*32;
    #pragma unroll
    for (int i=0;i<2;i++){
      int row = i*64 + w*16 + (lane>>2);
      int cb  = lane&3;
      gl_lds16(xb   + (size_t)(m0+row)*Ddim + k0 + cb*8, (char*)smem + i*4096 + w*1024);
      gl_lds16(Bsrc + (size_t)(n0+row)*Ddim + k0 + cb*8, (char*)smem + 8192 + i*4096 + w*1024);
    }
    __syncthreads();
    bf16x8 af[4], bfr[4];
    #pragma unroll
    for (int i=0;i<4;i++){
      af[i]  = *(const bf16x8*)&smem[(wm*64 + i*16 + l15)*32 + l4*8];
      bfr[i] = *(const bf16x8*)&smem[4096 + (wn*64 + i*16 + l15)*32 + l4*8];
    }
    #pragma unroll
    for (int i=0;i<4;i++)
      #pragma unroll
      for (int j=0;j<4;j++)
        acc[i][j] = __builtin_amdgcn_mfma_f32_16x16x32_bf16(af[i], bfr[j], acc[i][j], 0,0,0);
    __syncthreads();
  }

  if (type < 2){
    unsigned short* Ob = (type==0 ? Qb : Kb) + (size_t)hrel*Mdim*Ddim;
    #pragma unroll
    for (int i=0;i<4;i++){
      int mb = m0 + wm*64 + i*16 + (l4<<2);
      #pragma unroll
      for (int j=0;j<4;j++){
        int col = n0 + wn*64 + j*16 + l15;
        #pragma unroll
        for (int r=0;r<4;r++)
          Ob[(size_t)permrow(mb + r)*Ddim + col] = f2bf(acc[i][j][r]);
      }
    }
  } else {
    // bounce-transpose tile through LDS, write Vt[d][m'] with parity-split columns
    #pragma unroll
    for (int i=0;i<4;i++){
      int ml = wm*64 + i*16 + (l4<<2);
      #pragma unroll
      for (int j=0;j<4;j++){
        int nl = wn*64 + j*16 + l15;
        #pragma unroll
        for (int r=0;r<4;r++)
          smem[(ml + r)*130 + nl] = f2bf(acc[i][j][r]);
      }
    }
    __syncthreads();
    unsigned short* Ovt = Vtb + (size_t)hrel*Ddim*Mdim;
    int bb  = m0 >> 11;
    int ib0 = (m0 & 2047) >> 1;     // i-base within parity block (64 i per tile)
    #pragma unroll
    for (int c=0;c<8;c++){
      int nl = c*16 + (tid>>4);     // d-local 0..127
      int il = (tid&15)*4;          // i-local 0..60 step 4
      #pragma unroll
      for (int pp=0; pp<2; pp++){
        union { unsigned short s[4]; uint2 v; } pk;
        #pragma unroll
        for (int ii=0;ii<4;ii++) pk.s[ii] = smem[(2*(il+ii)+pp)*130 + nl];
        *(uint2*)&Ovt[(size_t)(n0+nl)*Mdim + bb*Sdim + pp*Shalf + ib0 + il] = pk.v;
      }
    }
  }
}

// ---------------- staging (8 waves, bi = w*4+jj, 8 loads/wave) ----------------
// dense: no clamps (always in range); spec: clamped, 32-aligned tiles => clamped
// chunks are fully masked.
__device__ __forceinline__ void stage_dense(const unsigned short* Kbase, int krow0,
                                            const unsigned short* Vblk, int vcol0,
                                            char* KsB, char* VsB, int w, int lane)
{
  int l15 = lane&15, l4 = lane>>4;
  #pragma unroll
  for (int jj=0;jj<4;jj++){
    int bi = w*4 + jj;
    int row = krow0 + ((bi>>4)<<4) + l15;
    int g   = ((bi&15)<<2) + l4;
    gl_lds16(Kbase + ((size_t)row<<9) + g*8, KsB + bi*1024);
    int d   = (bi<<4) + l15;
    int col = vcol0 + l4*8;
    gl_lds16(Vblk + ((size_t)d<<13) + col, VsB + bi*1024);
  }
}
__device__ __forceinline__ void stage_spec(const unsigned short* Kbase, int krow0,
                                           const unsigned short* Vblk, int vcol0,
                                           char* KsB, char* VsB, int w, int lane)
{
  int l15 = lane&15, l4 = lane>>4;
  #pragma unroll
  for (int jj=0;jj<4;jj++){
    int bi = w*4 + jj;
    int row = krow0 + ((bi>>4)<<4) + l15;
    row = row < 0 ? 0 : (row > Shalf-1 ? Shalf-1 : row);
    int g   = ((bi&15)<<2) + l4;
    gl_lds16(Kbase + ((size_t)row<<9) + g*8, KsB + bi*1024);
    int d   = (bi<<4) + l15;
    int col = vcol0 + l4*8;
    col = col < 0 ? 0 : (col > Shalf-8 ? Shalf-8 : col);
    gl_lds16(Vblk + ((size_t)d<<13) + col, VsB + bi*1024);
  }
}

// ---------------- flash attention over parity-dense sequences ----------------
#define NDENSE 32
#define NSPEC 5
#define NT (NDENSE + NSPEC)

__launch_bounds__(512, 2)
__global__ void attn(const unsigned short* __restrict__ Qb,
                     const unsigned short* __restrict__ Kb,
                     const unsigned short* __restrict__ Vtb,
                     float* __restrict__ out)
{
  __shared__ char lds[2*32768 + 2*32768 + 8*1024];   // Ks dbuf | Vs dbuf | Ps per-wave
  int tid = threadIdx.x, w = tid>>6, lane = tid&63;
  int l15 = lane&15, l4 = lane>>4;
  // grid = (z, qc): linear id = z + 64*qc -> XCD = z%8, so all 8 q-chunks of one
  // (h,b,p) stream land on the same XCD's L2.
  int z  = blockIdx.x;              // ((h*4+b)*2+p)
  int qc = blockIdx.y;              // 0..7 (128 queries each)
  int p  = z & 1; int zb = z >> 1; int b = zb & 3; int h = zb >> 2;

  const unsigned short* Qp     = Qb + (size_t)h*Mdim*Ddim + (size_t)(b*Sdim + p*Shalf)*Ddim;
  const unsigned short* Ksame  = Kb + (size_t)h*Mdim*Ddim + (size_t)(b*Sdim + p*Shalf)*Ddim;
  const unsigned short* Kopp   = Kb + (size_t)h*Mdim*Ddim + (size_t)(b*Sdim + (1-p)*Shalf)*Ddim;
  const unsigned short* Vt     = Vtb + (size_t)h*Ddim*Mdim;
  int csame = b*Sdim + p*Shalf;
  int copp  = b*Sdim + (1-p)*Shalf;
  int i0 = qc*128;
  int j0 = i0 - 32 + 32*p;          // parity-trimmed 32-aligned neighbor-window base

  // Q fragments in registers: rows i0 + w*16 + l15
  bf16x8 qa[16];
  {
    const unsigned short* qr = Qp + (size_t)(i0 + w*16 + l15)*Ddim;
    #pragma unroll
    for (int ks=0;ks<16;ks++) qa[ks] = *(const bf16x8*)&qr[ks*32 + l4*8];
  }

  f32x4 acc[32];
  #pragma unroll
  for (int n=0;n<32;n++){ f32x4 zz={0.f,0.f,0.f,0.f}; acc[n]=zz; }
  float ms[4], lp[4];
  #pragma unroll
  for (int r=0;r<4;r++){ ms[r] = -3.0e38f; lp[r] = 0.f; }

  // prologue: stage tile 0 (dense, fully in-range)
  stage_dense(Ksame, 0, Vt + csame, 0, lds, lds + 65536, w, lane);

  for (int t=0; t<NT; ++t){
    int buf = t & 1;
    char* KsB = lds + buf*32768;
    char* VsB = lds + 65536 + buf*32768;

    __builtin_amdgcn_sched_barrier(0);
    __builtin_amdgcn_s_barrier();            // all waves done reading buf^1 (tile t-1)
    if (t + 1 < NT){
      char* KsN = lds + (buf^1)*32768;
      char* VsN = lds + 65536 + (buf^1)*32768;
      if (t + 1 < NDENSE)
        stage_dense(Ksame, (t+1)*32, Vt + csame, (t+1)*32, KsN, VsN, w, lane);
      else {
        int tt = t + 1 - NDENSE;
        stage_spec(Kopp, j0 + tt*32, Vt + copp, j0 + tt*32, KsN, VsN, w, lane);
      }
      asm volatile("s_waitcnt vmcnt(8)" ::: "memory");   // tile t's 8 loads done; t+1 in flight
    } else {
      asm volatile("s_waitcnt vmcnt(0)" ::: "memory");
    }
    __builtin_amdgcn_s_barrier();            // publish tile t across waves
    __builtin_amdgcn_sched_barrier(0);

    // QK^T : S[16 q][32 keys] per wave (split even/odd accumulator chains)
    f32x4 sc[2];
    #pragma unroll
    for (int sub=0; sub<2; ++sub){
      f32x4 ae = {0.f,0.f,0.f,0.f}, ao = {0.f,0.f,0.f,0.f};
      #pragma unroll
      for (int ks=0;ks<16;ks+=2){
        bf16x8 k0 = *(const bf16x8*)(KsB + (sub*16+ks)*1024   + (l4*16+l15)*16);
        bf16x8 k1 = *(const bf16x8*)(KsB + (sub*16+ks+1)*1024 + (l4*16+l15)*16);
        ae = __builtin_amdgcn_mfma_f32_16x16x32_bf16(qa[ks],   k0, ae, 0,0,0);
        ao = __builtin_amdgcn_mfma_f32_16x16x32_bf16(qa[ks+1], k1, ao, 0,0,0);
      }
      sc[sub] = ae + ao;
    }

    // softmax: defer-max; cross-lane max only when triggered; row-sum deferred
    float s0v[4], s1v[4], lmax[4];
    bool spec = (t >= NDENSE);
    int tbase = spec ? (j0 + (t-NDENSE)*32) : 0;
    #pragma unroll
    for (int r=0;r<4;r++){
      float s0 = sc[0][r]*SCALE, s1 = sc[1][r]*SCALE;
      if (spec){
        int iq = i0 + w*16 + l4*4 + r;
        int jA = tbase + l15;
        int jB = jA + 16;
        int tgt = iq - 1 + 2*p;
        bool vA = (jA>=0) & (jA<Shalf) & ((jA==iq) | (jA==tgt));
        bool vB = (jB>=0) & (jB<Shalf) & ((jB==iq) | (jB==tgt));
        if(!vA) s0 = -1e30f;
        if(!vB) s1 = -1e30f;
      }
      s0v[r]=s0; s1v[r]=s1;
      lmax[r] = fmaxf(s0, s1);
    }
    bool need = (lmax[0] > ms[0]+8.f) | (lmax[1] > ms[1]+8.f) |
                (lmax[2] > ms[2]+8.f) | (lmax[3] > ms[3]+8.f);
    if (__any(need)){
      #pragma unroll
      for (int r=0;r<4;r++){
        float tm = lmax[r];
        tm = fmaxf(tm, __shfl_xor(tm, 1));
        tm = fmaxf(tm, __shfl_xor(tm, 2));
        tm = fmaxf(tm, __shfl_xor(tm, 4));
        tm = fmaxf(tm, __shfl_xor(tm, 8));
        float nm = fmaxf(ms[r], tm);
        float rs = exp2f((ms[r]-nm)*LOG2E);
        ms[r] = nm; lp[r] *= rs;
        #pragma unroll
        for (int n=0;n<32;n++) acc[n][r] *= rs;
      }
    }

    // P = exp(s - m); per-lane partial row-sum; store P to per-wave LDS (A-frag layout)
    char* PsB = lds + 131072 + w*1024;
    #pragma unroll
    for (int r=0;r<4;r++){
      float p0 = exp2f((s0v[r]-ms[r])*LOG2E);
      float p1 = exp2f((s1v[r]-ms[r])*LOG2E);
      lp[r] += p0 + p1;
      int q = l4*4 + r;
      *(unsigned short*)(PsB + (((l15>>3)*16 + q)*16 + (l15&7)*2))     = f2bf(p0);
      *(unsigned short*)(PsB + (((2+(l15>>3))*16 + q)*16 + (l15&7)*2)) = f2bf(p1);
    }
    asm volatile("s_waitcnt lgkmcnt(0)" ::: "memory");
    __builtin_amdgcn_sched_barrier(0);
    bf16x8 pa = *(const bf16x8*)(PsB + (l4*16+l15)*16);

    // PV: acc[n] over 32 d-fragments
    #pragma unroll
    for (int n=0;n<32;n++){
      bf16x8 vb = *(const bf16x8*)(VsB + n*1024 + (l4*16+l15)*16);
      acc[n] = __builtin_amdgcn_mfma_f32_16x16x32_bf16(pa, vb, acc[n], 0,0,0);
    }
  }

  // epilogue: reduce row-sums once, normalize + head-mean via atomics
  #pragma unroll
  for (int r=0;r<4;r++){
    float t = lp[r];
    t += __shfl_xor(t, 1);
    t += __shfl_xor(t, 2);
    t += __shfl_xor(t, 4);
    t += __shfl_xor(t, 8);
    float inv = 0.125f / t;
    int i = i0 + w*16 + l4*4 + r;
    float* orow = out + (size_t)(b*Sdim + 2*i + p)*Ddim;
    #pragma unroll
    for (int n=0;n<32;n++)
      atomicAdd(&orow[n*16 + l15], acc[n][r]*inv);
  }
}

extern "C" void kernel_launch(void* const* d_in, const int* in_sizes, int n_in,
                              void* d_out, int out_size, void* d_ws, size_t ws_size,
                              hipStream_t stream)
{
  (void)in_sizes; (void)n_in;
  const float* x  = (const float*)d_in[0];
  const float* Wq = (const float*)d_in[1];
  const float* Wk = (const float*)d_in[2];
  const float* Wv = (const float*)d_in[3];
  float* out = (float*)d_out;

  const size_t xb_bytes = (size_t)Mdim*Ddim*2;        // 8 MB
  const size_t wt_bytes = (size_t)3*Hdim*Ddim*Ddim*2; // 12.6 MB
  const size_t per_head = (size_t)Mdim*Ddim*2;        // 8.4 MB

  int g = 8;
  while (g > 1 && xb_bytes + wt_bytes + 3*(size_t)g*per_head > ws_size) g >>= 1;

  unsigned short* xb  = (unsigned short*)d_ws;
  unsigned short* Wt  = (unsigned short*)((char*)d_ws + xb_bytes);
  unsigned short* Qb  = (unsigned short*)((char*)d_ws + xb_bytes + wt_bytes);
  unsigned short* Kb  = Qb + (size_t)g*Mdim*Ddim;
  unsigned short* Vtb = Kb + (size_t)g*Mdim*Ddim;

  hipMemsetAsync(d_out, 0, (size_t)out_size*sizeof(float), stream);
  cvt_x<<<dim3(Mdim*Ddim/8/256), dim3(256), 0, stream>>>(x, xb, Mdim*Ddim/8);
  twk<<<dim3(Ddim/32, Ddim/32, 3*Hdim), dim3(32,8), 0, stream>>>(Wq, Wk, Wv, Wt);

  for (int h0 = 0; h0 < Hdim; h0 += g){
    proj<<<dim3(Mdim/128, 12*g), dim3(256), 0, stream>>>(xb, Wt, Qb, Kb, Vtb, h0, g);
    attn<<<dim3(g*Bdim*2, Shalf/128 /*qc=8*/), dim3(512), 0, stream>>>(Qb, Kb, Vtb, out);
  }
}